// Round 3
// baseline (252.011 us; speedup 1.0000x reference)
//
#include <hip/hip_runtime.h>
#include <math.h>

// ============================================================================
// Mathematical collapse of the reference:
//   h = broadcast(z) over N_NODES  =>  all nodes identical within a batch.
//   Every layer is per-node => h stays rank-1 (one vector per batch).
//   Attention: all scores equal => softmax uniform => o = mean_k(v) = v.
//   Edge logits la[b]+lb[b]+fin_b are ONE 2-vector c[b] for ALL pairs.
//   Straight-through gumbel: y = y_hard exactly (y_soft - y_soft == 0 bitwise).
//   tau = |temp| > 0 is argmax-invariant; argmax tie -> index 0 -> use >=.
//   => e[b,p] = (c0 + g0(u0) >= c1 + g1(u1)),  g(u) = -log(-log(u+1e-10)+1e-10)
//   => adj[b,i,j] = e at (min,max) pair, 0 on diagonal, symmetric.
//
// Kernel 1 (head): per-batch tiny MLP in f64 — one-time, ~5 us, 16 blocks.
// Kernel 2 (adj_tile): 64x64 tile-PAIR kernel. Each block computes one upper
//   tile's e values (u read exactly once, coalesced), writes the upper tile
//   directly and the mirrored lower tile via an LDS transpose (pad 65 ->
//   worst-case 2-way bank conflicts = free). All global writes are float4.
//   HBM traffic = 67 MB read + 67 MB write = the true floor (~21 us).
//   Gumbel via f32 hardware logf (f64 log would be ~100 us of VALU).
// ============================================================================

#define NN    1024
#define HD    256
#define DIN0  71
#define NPAIR 523776   // 1024*1023/2
#define TILE  64
#define NT    16       // NN / TILE

// ---------------------------------------------------------------------------
// head kernel helpers (f64, one 256-thread block per batch)
// ---------------------------------------------------------------------------
__device__ __forceinline__ double blk_reduce(double v, double* red) {
  const int t = threadIdx.x;
  red[t] = v;
  __syncthreads();
  #pragma unroll
  for (int s = 128; s > 0; s >>= 1) {
    if (t < s) red[t] += red[t + s];
    __syncthreads();
  }
  double r = red[0];
  __syncthreads();
  return r;
}

// LayerNorm src -> dst over D elements (D <= 256). Safe for src == dst.
__device__ __forceinline__ void ln_to(const double* src, double* dst, int D,
                                      const float* __restrict__ gam,
                                      const float* __restrict__ bet,
                                      double* red) {
  const int tid = threadIdx.x;
  double v = (tid < D) ? src[tid] : 0.0;
  double m = blk_reduce(v, red) / (double)D;
  double d = (tid < D) ? (src[tid] - m) : 0.0;
  double var = blk_reduce(d * d, red) / (double)D;
  double inv = 1.0 / sqrt(var + (double)1e-5f);  // f32-rounded EPS, like jnp
  if (tid < D) dst[tid] = d * inv * (double)gam[tid] + (double)bet[tid];
  __syncthreads();
}

__device__ __forceinline__ double dotw(const double* src, int Din,
                                       const float* __restrict__ W, int row) {
  const float* wr = W + (size_t)row * Din;
  double acc = 0.0;
  if ((Din & 3) == 0) {
    const float4* w4 = reinterpret_cast<const float4*>(wr);
    const int n4 = Din >> 2;
    #pragma unroll 4
    for (int i = 0; i < n4; ++i) {
      float4 w = w4[i];
      acc += src[4*i+0] * (double)w.x;
      acc += src[4*i+1] * (double)w.y;
      acc += src[4*i+2] * (double)w.z;
      acc += src[4*i+3] * (double)w.w;
    }
  } else {
    for (int i = 0; i < Din; ++i) acc += src[i] * (double)wr[i];
  }
  return acc;
}

__device__ __forceinline__ double gelu_exact(double x) {
  return 0.5 * x * (1.0 + erf(x * 0.70710678118654752440));
}

__global__ __launch_bounds__(256)
void head_kernel(const float* __restrict__ x, const float* __restrict__ stats,
                 const float* __restrict__ ln0_g, const float* __restrict__ ln0_b,
                 const float* __restrict__ rb1_ln_g, const float* __restrict__ rb1_ln_b,
                 const float* __restrict__ rb1_w1, const float* __restrict__ rb1_b1,
                 const float* __restrict__ rb1_w2, const float* __restrict__ rb1_b2,
                 const float* __restrict__ rb1_wp, const float* __restrict__ rb1_bp,
                 const float* __restrict__ rb2_ln_g, const float* __restrict__ rb2_ln_b,
                 const float* __restrict__ rb2_w1, const float* __restrict__ rb2_b1,
                 const float* __restrict__ rb2_w2, const float* __restrict__ rb2_b2,
                 const float* __restrict__ att_ln_g, const float* __restrict__ att_ln_b,
                 const float* __restrict__ att_win, const float* __restrict__ att_bin,
                 const float* __restrict__ att_wout, const float* __restrict__ att_bout,
                 const float* __restrict__ out_w, const float* __restrict__ out_b,
                 const float* __restrict__ fin_w, const float* __restrict__ fin_b,
                 double* __restrict__ c_out) {
  __shared__ double h[HD], t[HD], g[HD], red[256];
  const int tid = threadIdx.x;
  const int b = blockIdx.x;

  // z = concat(x[b], stats[b])
  if (tid < DIN0)
    h[tid] = (tid < 64) ? (double)x[b * 64 + tid] : (double)stats[b * 7 + tid - 64];
  __syncthreads();

  // ln0 (in place)
  ln_to(h, h, DIN0, ln0_g, ln0_b, red);

  // ---- residual block 1 (D0 -> H, with projection) ----
  ln_to(h, t, DIN0, rb1_ln_g, rb1_ln_b, red);
  g[tid] = gelu_exact(dotw(t, DIN0, rb1_w1, tid) + (double)rb1_b1[tid]);
  __syncthreads();
  {
    double t2 = dotw(g, HD, rb1_w2, tid) + (double)rb1_b2[tid];
    double pr = dotw(h, DIN0, rb1_wp, tid) + (double)rb1_bp[tid];
    __syncthreads();          // everyone done reading h[0..70]
    h[tid] = t2 + pr;
  }
  __syncthreads();

  // ---- residual block 2 (H -> H) ----
  ln_to(h, t, HD, rb2_ln_g, rb2_ln_b, red);
  g[tid] = gelu_exact(dotw(t, HD, rb2_w1, tid) + (double)rb2_b1[tid]);
  __syncthreads();
  {
    double t2 = dotw(g, HD, rb2_w2, tid) + (double)rb2_b2[tid];
    h[tid] = h[tid] + t2;     // own index only; no cross-thread hazard
  }
  __syncthreads();

  // ---- attention (collapses to o = v) ----
  ln_to(h, t, HD, att_ln_g, att_ln_b, red);
  g[tid] = dotw(t, HD, att_win + 2 * HD * HD, tid) + (double)att_bin[2 * HD + tid]; // v slice
  __syncthreads();
  t[tid] = dotw(g, HD, att_wout, tid) + (double)att_bout[tid];
  __syncthreads();
  double hj = dotw(t, HD, out_w, tid) + (double)out_b[tid];

  // ---- edge logits: c[k] = sum_i h_i*(fin_w[k,i] + fin_w[k,H+i]) + fin_b[k] ----
  double v0 = hj * (double)fin_w[tid]          + hj * (double)fin_w[HD + tid];
  double v1 = hj * (double)fin_w[2 * HD + tid] + hj * (double)fin_w[3 * HD + tid];
  double c0 = blk_reduce(v0, red) + (double)fin_b[0];
  double c1 = blk_reduce(v1, red) + (double)fin_b[1];
  if (tid == 0) {
    c_out[2 * b + 0] = c0;
    c_out[2 * b + 1] = c1;
  }
}

// ---------------------------------------------------------------------------
// adj tile-pair kernel
// grid = (136 tile-pairs, 16 batches), 256 threads.
// Each block: tile-pair (ti <= tj). Stage 1 computes e for all (i<j) in the
// tile into LDS (and, for off-diagonal pairs, writes the upper tile directly
// from registers, coalesced). Stage 2 writes the mirrored lower tile (LDS
// transpose) or, for diagonal tiles, the full select (upper/mirror/0).
// ---------------------------------------------------------------------------
__global__ __launch_bounds__(256)
void adj_tile_kernel(const float* __restrict__ u, const double* __restrict__ c,
                     float* __restrict__ out) {
  __shared__ float tile[TILE][TILE + 1];   // pad 65 -> <=2-way conflicts (free)
  const int b = blockIdx.y;
  int k = blockIdx.x;                       // 0..135 -> (ti, tj), ti <= tj
  int ti = 0;
  while (k >= NT - ti) { k -= NT - ti; ++ti; }
  const int tj = ti + k;
  const bool diag = (ti == tj);

  const int t        = threadIdx.x;
  const int lane_col = (t & 15) << 2;       // 0..60 step 4
  const int row_base = t >> 4;              // 0..15
  const double c0 = c[2 * b + 0];
  const double c1 = c[2 * b + 1];
  const float* ub = u + (size_t)b * (2u * NPAIR);
  float* ob = out + ((size_t)b << 20);

  // ---- stage 1: compute e, fill LDS; direct upper write for off-diag ----
  #pragma unroll
  for (int s = 0; s < 4; ++s) {
    const int il = s * 16 + row_base;
    const int i  = ti * TILE + il;
    const int rb = i * (2 * NN - 1 - i) / 2 - i - 1;   // p = rb + j  (for j>i)
    float4 ev4;
    float* ev = &ev4.x;
    #pragma unroll
    for (int q = 0; q < 4; ++q) {
      const int jl = lane_col + q;
      const int j  = tj * TILE + jl;
      float e = 0.0f;
      if (j > i) {
        const int p = rb + j;
        const float2 uu = *reinterpret_cast<const float2*>(ub + 2 * p);
        // f32 hardware logs, mirroring the reference's own f32 ops.
        const float g0 = -logf(-logf(uu.x + 1e-10f) + 1e-10f);
        const float g1 = -logf(-logf(uu.y + 1e-10f) + 1e-10f);
        // Decision compare in f64 against the f64-accurate c.
        e = ((c0 + (double)g0) >= (c1 + (double)g1)) ? 1.0f : 0.0f;
      }
      ev[q] = e;
      tile[il][jl] = e;
    }
    if (!diag) {
      // coalesced float4 upper-tile write straight from registers
      *reinterpret_cast<float4*>(ob + (size_t)i * NN + tj * TILE + lane_col) = ev4;
    }
  }
  __syncthreads();

  // ---- stage 2: mirrored lower tile (off-diag) or full select (diag) ----
  #pragma unroll
  for (int s = 0; s < 4; ++s) {
    const int rl = s * 16 + row_base;
    if (!diag) {
      // lower tile row j = tj*64+rl, cols i = ti*64 + lane_col+q:
      // value = e(i, j) = tile[lane_col+q][rl]  (LDS transpose read, 2-way)
      float4 v = make_float4(tile[lane_col + 0][rl], tile[lane_col + 1][rl],
                             tile[lane_col + 2][rl], tile[lane_col + 3][rl]);
      *reinterpret_cast<float4*>(ob + (size_t)(tj * TILE + rl) * NN
                                    + ti * TILE + lane_col) = v;
    } else {
      float v[4];
      #pragma unroll
      for (int q = 0; q < 4; ++q) {
        const int jl = lane_col + q;
        v[q] = (jl > rl) ? tile[rl][jl] : ((jl < rl) ? tile[jl][rl] : 0.0f);
      }
      *reinterpret_cast<float4*>(ob + (size_t)(ti * TILE + rl) * NN
                                    + ti * TILE + lane_col)
          = make_float4(v[0], v[1], v[2], v[3]);
    }
  }
}

extern "C" void kernel_launch(void* const* d_in, const int* in_sizes, int n_in,
                              void* d_out, int out_size, void* d_ws, size_t ws_size,
                              hipStream_t stream) {
  const float* x        = (const float*)d_in[0];
  const float* stats    = (const float*)d_in[1];
  const float* u        = (const float*)d_in[2];
  const float* ln0_g    = (const float*)d_in[3];
  const float* ln0_b    = (const float*)d_in[4];
  const float* rb1_ln_g = (const float*)d_in[5];
  const float* rb1_ln_b = (const float*)d_in[6];
  const float* rb1_w1   = (const float*)d_in[7];
  const float* rb1_b1   = (const float*)d_in[8];
  const float* rb1_w2   = (const float*)d_in[9];
  const float* rb1_b2   = (const float*)d_in[10];
  const float* rb1_wp   = (const float*)d_in[11];
  const float* rb1_bp   = (const float*)d_in[12];
  const float* rb2_ln_g = (const float*)d_in[13];
  const float* rb2_ln_b = (const float*)d_in[14];
  const float* rb2_w1   = (const float*)d_in[15];
  const float* rb2_b1   = (const float*)d_in[16];
  const float* rb2_w2   = (const float*)d_in[17];
  const float* rb2_b2   = (const float*)d_in[18];
  const float* att_ln_g = (const float*)d_in[19];
  const float* att_ln_b = (const float*)d_in[20];
  const float* att_win  = (const float*)d_in[21];
  const float* att_bin  = (const float*)d_in[22];
  const float* att_wout = (const float*)d_in[23];
  const float* att_bout = (const float*)d_in[24];
  const float* out_w    = (const float*)d_in[25];
  const float* out_b    = (const float*)d_in[26];
  const float* fin_w    = (const float*)d_in[27];
  const float* fin_b    = (const float*)d_in[28];
  // d_in[29] = temp: tau = |temp| > 0 is argmax-invariant -> unused.

  double* c_ws = (double*)d_ws;          // 32 doubles
  float* out   = (float*)d_out;          // [16, 1024, 1024]

  hipLaunchKernelGGL(head_kernel, dim3(16), dim3(256), 0, stream,
                     x, stats, ln0_g, ln0_b,
                     rb1_ln_g, rb1_ln_b, rb1_w1, rb1_b1, rb1_w2, rb1_b2, rb1_wp, rb1_bp,
                     rb2_ln_g, rb2_ln_b, rb2_w1, rb2_b1, rb2_w2, rb2_b2,
                     att_ln_g, att_ln_b, att_win, att_bin, att_wout, att_bout,
                     out_w, out_b, fin_w, fin_b, c_ws);

  hipLaunchKernelGGL(adj_tile_kernel, dim3(NT * (NT + 1) / 2, 16), dim3(256), 0, stream,
                     u, c_ws, out);
}

// Round 4
// 248.047 us; speedup vs baseline: 1.0160x; 1.0160x over previous
//
#include <hip/hip_runtime.h>
#include <math.h>

// ============================================================================
// Mathematical collapse of the reference:
//   h = broadcast(z) over N_NODES  =>  all nodes identical within a batch.
//   Every layer is per-node => h stays rank-1 (one vector per batch).
//   Attention: all scores equal => softmax uniform => o = mean_k(v) = v.
//   Edge logits la[b]+lb[b]+fin_b are ONE 2-vector c[b] for ALL pairs.
//   Straight-through gumbel: y = y_hard exactly (y_soft - y_soft == 0 bitwise).
//   tau = |temp| > 0 is argmax-invariant; argmax tie -> index 0 -> use >=.
//   => e[b,p] = (c0 + g0(u0) >= c1 + g1(u1)),  g(u) = -log(-log(u+1e-10)+1e-10)
//   => adj[b,i,j] = e at (min,max) pair, 0 on diagonal, symmetric.
//
// R3 lesson (rocprof): head_kernel was 70us — latency-bound weight fetch
//   (6.9MB FETCH at ~100GB/s effective, 16 blocks, 0.68% occupancy).
// Fix: (a) wide prefetch kernel pulls all weight matrices into every XCD's
//   L2 first (stripe = bid>>3 appears once per XCD under round-robin
//   dispatch); (b) 4-accumulator dotw breaks the 256-long f64 FMA chain;
//   (c) shuffle-based block reduce (2 barriers instead of 9).
// ============================================================================

#define NN    1024
#define HD    256
#define DIN0  71
#define NPAIR 523776   // 1024*1023/2
#define TILE  64
#define NT    16       // NN / TILE

// ---------------------------------------------------------------------------
// prefetch kernel: touch all weight matrices with a wide grid so each XCD's
// L2 holds them before head_kernel runs. stripe=bid>>3 -> blocks 8s..8s+7
// carry stripe s to all 8 XCDs. 2048 blocks x 256 thr.
// ---------------------------------------------------------------------------
__device__ __forceinline__ float pf_sum(const float4* __restrict__ p, int n4,
                                        int stripe, int tid) {
  float s = 0.0f;
  for (int i = stripe * 256 + tid; i < n4; i += 256 * 256) {
    float4 v = p[i];
    s += v.x + v.y + v.z + v.w;
  }
  return s;
}

__global__ __launch_bounds__(256)
void prefetch_kernel(const float* __restrict__ w0, int n0,
                     const float* __restrict__ w1, int n1,
                     const float* __restrict__ w2, int n2,
                     const float* __restrict__ w3, int n3,
                     const float* __restrict__ w4, int n4_,
                     const float* __restrict__ w5, int n5,
                     const float* __restrict__ w6, int n6,
                     const float* __restrict__ w7, int n7,
                     const float* __restrict__ w8, int n8,
                     float* __restrict__ sink) {
  const int stripe = blockIdx.x >> 3;
  const int tid = threadIdx.x;
  float s = 0.0f;
  s += pf_sum((const float4*)w0, n0 >> 2, stripe, tid);
  s += pf_sum((const float4*)w1, n1 >> 2, stripe, tid);
  s += pf_sum((const float4*)w2, n2 >> 2, stripe, tid);
  s += pf_sum((const float4*)w3, n3 >> 2, stripe, tid);
  s += pf_sum((const float4*)w4, n4_ >> 2, stripe, tid);
  s += pf_sum((const float4*)w5, n5 >> 2, stripe, tid);
  s += pf_sum((const float4*)w6, n6 >> 2, stripe, tid);
  s += pf_sum((const float4*)w7, n7 >> 2, stripe, tid);
  s += pf_sum((const float4*)w8, n8 >> 2, stripe, tid);
  // DCE guard: condition is (unprovably) never true; loads must execute.
  if (s == 123456789.0f) sink[0] = s;
}

// ---------------------------------------------------------------------------
// head kernel helpers (f64, one 256-thread block per batch)
// ---------------------------------------------------------------------------
__device__ __forceinline__ double blk_reduce(double v, double* red) {
  // intra-wave butterfly (64 lanes), then cross-wave via LDS (4 waves)
  #pragma unroll
  for (int m = 32; m > 0; m >>= 1) v += __shfl_xor(v, m, 64);
  const int wid = threadIdx.x >> 6;
  __syncthreads();                 // red[] free from any previous use
  if ((threadIdx.x & 63) == 0) red[wid] = v;
  __syncthreads();
  return (red[0] + red[1]) + (red[2] + red[3]);  // same order on all threads
}

// LayerNorm src -> dst over D elements (D <= 256). Safe for src == dst.
__device__ __forceinline__ void ln_to(const double* src, double* dst, int D,
                                      const float* __restrict__ gam,
                                      const float* __restrict__ bet,
                                      double* red) {
  const int tid = threadIdx.x;
  double v = (tid < D) ? src[tid] : 0.0;
  double m = blk_reduce(v, red) / (double)D;
  double d = (tid < D) ? (src[tid] - m) : 0.0;
  double var = blk_reduce(d * d, red) / (double)D;
  double inv = 1.0 / sqrt(var + (double)1e-5f);  // f32-rounded EPS, like jnp
  if (tid < D) dst[tid] = d * inv * (double)gam[tid] + (double)bet[tid];
  __syncthreads();
}

// dot(src[0..Din), W[row, :]) in f64; 4 independent accumulator chains.
__device__ __forceinline__ double dotw(const double* src, int Din,
                                       const float* __restrict__ W, int row) {
  const float* wr = W + (size_t)row * Din;
  if ((Din & 3) == 0) {
    const float4* w4 = reinterpret_cast<const float4*>(wr);
    const int n4 = Din >> 2;
    double a0 = 0.0, a1 = 0.0, a2 = 0.0, a3 = 0.0;
    #pragma unroll 4
    for (int i = 0; i < n4; ++i) {
      float4 w = w4[i];
      a0 += src[4*i+0] * (double)w.x;
      a1 += src[4*i+1] * (double)w.y;
      a2 += src[4*i+2] * (double)w.z;
      a3 += src[4*i+3] * (double)w.w;
    }
    return (a0 + a1) + (a2 + a3);
  }
  double acc = 0.0;
  for (int i = 0; i < Din; ++i) acc += src[i] * (double)wr[i];
  return acc;
}

__device__ __forceinline__ double gelu_exact(double x) {
  return 0.5 * x * (1.0 + erf(x * 0.70710678118654752440));
}

__global__ __launch_bounds__(256)
void head_kernel(const float* __restrict__ x, const float* __restrict__ stats,
                 const float* __restrict__ ln0_g, const float* __restrict__ ln0_b,
                 const float* __restrict__ rb1_ln_g, const float* __restrict__ rb1_ln_b,
                 const float* __restrict__ rb1_w1, const float* __restrict__ rb1_b1,
                 const float* __restrict__ rb1_w2, const float* __restrict__ rb1_b2,
                 const float* __restrict__ rb1_wp, const float* __restrict__ rb1_bp,
                 const float* __restrict__ rb2_ln_g, const float* __restrict__ rb2_ln_b,
                 const float* __restrict__ rb2_w1, const float* __restrict__ rb2_b1,
                 const float* __restrict__ rb2_w2, const float* __restrict__ rb2_b2,
                 const float* __restrict__ att_ln_g, const float* __restrict__ att_ln_b,
                 const float* __restrict__ att_win, const float* __restrict__ att_bin,
                 const float* __restrict__ att_wout, const float* __restrict__ att_bout,
                 const float* __restrict__ out_w, const float* __restrict__ out_b,
                 const float* __restrict__ fin_w, const float* __restrict__ fin_b,
                 double* __restrict__ c_out) {
  __shared__ double h[HD], t[HD], g[HD], red[8];
  const int tid = threadIdx.x;
  const int b = blockIdx.x;

  // z = concat(x[b], stats[b])
  if (tid < DIN0)
    h[tid] = (tid < 64) ? (double)x[b * 64 + tid] : (double)stats[b * 7 + tid - 64];
  __syncthreads();

  // ln0 (in place)
  ln_to(h, h, DIN0, ln0_g, ln0_b, red);

  // ---- residual block 1 (D0 -> H, with projection) ----
  ln_to(h, t, DIN0, rb1_ln_g, rb1_ln_b, red);
  g[tid] = gelu_exact(dotw(t, DIN0, rb1_w1, tid) + (double)rb1_b1[tid]);
  __syncthreads();
  {
    double t2 = dotw(g, HD, rb1_w2, tid) + (double)rb1_b2[tid];
    double pr = dotw(h, DIN0, rb1_wp, tid) + (double)rb1_bp[tid];
    __syncthreads();          // everyone done reading h[0..70]
    h[tid] = t2 + pr;
  }
  __syncthreads();

  // ---- residual block 2 (H -> H) ----
  ln_to(h, t, HD, rb2_ln_g, rb2_ln_b, red);
  g[tid] = gelu_exact(dotw(t, HD, rb2_w1, tid) + (double)rb2_b1[tid]);
  __syncthreads();
  {
    double t2 = dotw(g, HD, rb2_w2, tid) + (double)rb2_b2[tid];
    h[tid] = h[tid] + t2;     // own index only; no cross-thread hazard
  }
  __syncthreads();

  // ---- attention (collapses to o = v) ----
  ln_to(h, t, HD, att_ln_g, att_ln_b, red);
  g[tid] = dotw(t, HD, att_win + 2 * HD * HD, tid) + (double)att_bin[2 * HD + tid]; // v slice
  __syncthreads();
  t[tid] = dotw(g, HD, att_wout, tid) + (double)att_bout[tid];
  __syncthreads();
  double hj = dotw(t, HD, out_w, tid) + (double)out_b[tid];

  // ---- edge logits: c[k] = sum_i h_i*(fin_w[k,i] + fin_w[k,H+i]) + fin_b[k] ----
  double v0 = hj * (double)fin_w[tid]          + hj * (double)fin_w[HD + tid];
  double v1 = hj * (double)fin_w[2 * HD + tid] + hj * (double)fin_w[3 * HD + tid];
  double c0 = blk_reduce(v0, red) + (double)fin_b[0];
  double c1 = blk_reduce(v1, red) + (double)fin_b[1];
  if (tid == 0) {
    c_out[2 * b + 0] = c0;
    c_out[2 * b + 1] = c1;
  }
}

// ---------------------------------------------------------------------------
// adj tile-pair kernel
// grid = (136 tile-pairs, 16 batches), 256 threads.
// ---------------------------------------------------------------------------
__global__ __launch_bounds__(256)
void adj_tile_kernel(const float* __restrict__ u, const double* __restrict__ c,
                     float* __restrict__ out) {
  __shared__ float tile[TILE][TILE + 1];   // pad 65 -> <=2-way conflicts (free)
  const int b = blockIdx.y;
  int k = blockIdx.x;                       // 0..135 -> (ti, tj), ti <= tj
  int ti = 0;
  while (k >= NT - ti) { k -= NT - ti; ++ti; }
  const int tj = ti + k;
  const bool diag = (ti == tj);

  const int t        = threadIdx.x;
  const int lane_col = (t & 15) << 2;       // 0..60 step 4
  const int row_base = t >> 4;              // 0..15
  const double c0 = c[2 * b + 0];
  const double c1 = c[2 * b + 1];
  const float* ub = u + (size_t)b * (2u * NPAIR);
  float* ob = out + ((size_t)b << 20);

  // ---- stage 1: compute e, fill LDS; direct upper write for off-diag ----
  #pragma unroll
  for (int s = 0; s < 4; ++s) {
    const int il = s * 16 + row_base;
    const int i  = ti * TILE + il;
    const int rb = i * (2 * NN - 1 - i) / 2 - i - 1;   // p = rb + j  (for j>i)
    float4 ev4;
    float* ev = &ev4.x;
    #pragma unroll
    for (int q = 0; q < 4; ++q) {
      const int jl = lane_col + q;
      const int j  = tj * TILE + jl;
      float e = 0.0f;
      if (j > i) {
        const int p = rb + j;
        const float2 uu = *reinterpret_cast<const float2*>(ub + 2 * p);
        // f32 hardware logs, mirroring the reference's own f32 ops.
        const float g0 = -logf(-logf(uu.x + 1e-10f) + 1e-10f);
        const float g1 = -logf(-logf(uu.y + 1e-10f) + 1e-10f);
        // Decision compare in f64 against the f64-accurate c.
        e = ((c0 + (double)g0) >= (c1 + (double)g1)) ? 1.0f : 0.0f;
      }
      ev[q] = e;
      tile[il][jl] = e;
    }
    if (!diag) {
      // coalesced float4 upper-tile write straight from registers
      *reinterpret_cast<float4*>(ob + (size_t)i * NN + tj * TILE + lane_col) = ev4;
    }
  }
  __syncthreads();

  // ---- stage 2: mirrored lower tile (off-diag) or full select (diag) ----
  #pragma unroll
  for (int s = 0; s < 4; ++s) {
    const int rl = s * 16 + row_base;
    if (!diag) {
      // lower tile row j = tj*64+rl, cols i = ti*64 + lane_col+q:
      // value = e(i, j) = tile[lane_col+q][rl]  (LDS transpose read, 2-way)
      float4 v = make_float4(tile[lane_col + 0][rl], tile[lane_col + 1][rl],
                             tile[lane_col + 2][rl], tile[lane_col + 3][rl]);
      *reinterpret_cast<float4*>(ob + (size_t)(tj * TILE + rl) * NN
                                    + ti * TILE + lane_col) = v;
    } else {
      float v[4];
      #pragma unroll
      for (int q = 0; q < 4; ++q) {
        const int jl = lane_col + q;
        v[q] = (jl > rl) ? tile[rl][jl] : ((jl < rl) ? tile[jl][rl] : 0.0f);
      }
      *reinterpret_cast<float4*>(ob + (size_t)(ti * TILE + rl) * NN
                                    + ti * TILE + lane_col)
          = make_float4(v[0], v[1], v[2], v[3]);
    }
  }
}

extern "C" void kernel_launch(void* const* d_in, const int* in_sizes, int n_in,
                              void* d_out, int out_size, void* d_ws, size_t ws_size,
                              hipStream_t stream) {
  const float* x        = (const float*)d_in[0];
  const float* stats    = (const float*)d_in[1];
  const float* u        = (const float*)d_in[2];
  const float* ln0_g    = (const float*)d_in[3];
  const float* ln0_b    = (const float*)d_in[4];
  const float* rb1_ln_g = (const float*)d_in[5];
  const float* rb1_ln_b = (const float*)d_in[6];
  const float* rb1_w1   = (const float*)d_in[7];
  const float* rb1_b1   = (const float*)d_in[8];
  const float* rb1_w2   = (const float*)d_in[9];
  const float* rb1_b2   = (const float*)d_in[10];
  const float* rb1_wp   = (const float*)d_in[11];
  const float* rb1_bp   = (const float*)d_in[12];
  const float* rb2_ln_g = (const float*)d_in[13];
  const float* rb2_ln_b = (const float*)d_in[14];
  const float* rb2_w1   = (const float*)d_in[15];
  const float* rb2_b1   = (const float*)d_in[16];
  const float* rb2_w2   = (const float*)d_in[17];
  const float* rb2_b2   = (const float*)d_in[18];
  const float* att_ln_g = (const float*)d_in[19];
  const float* att_ln_b = (const float*)d_in[20];
  const float* att_win  = (const float*)d_in[21];
  const float* att_bin  = (const float*)d_in[22];
  const float* att_wout = (const float*)d_in[23];
  const float* att_bout = (const float*)d_in[24];
  const float* out_w    = (const float*)d_in[25];
  const float* out_b    = (const float*)d_in[26];
  const float* fin_w    = (const float*)d_in[27];
  const float* fin_b    = (const float*)d_in[28];
  // d_in[29] = temp: tau = |temp| > 0 is argmax-invariant -> unused.

  double* c_ws = (double*)d_ws;          // 32 doubles
  float* sink  = (float*)d_ws + 64;      // prefetch DCE guard (never written)
  float* out   = (float*)d_out;          // [16, 1024, 1024]

  // warm every XCD's L2 with the weight matrices (head is latency-bound on
  // these: 70us -> target <15us).
  hipLaunchKernelGGL(prefetch_kernel, dim3(2048), dim3(256), 0, stream,
                     rb1_w1, HD * DIN0 - (HD * DIN0 % 4),   // 18176 floats
                     rb1_w2, HD * HD,
                     rb1_wp, HD * DIN0 - (HD * DIN0 % 4),
                     rb2_w1, HD * HD,
                     rb2_w2, HD * HD,
                     att_win + 2 * HD * HD, HD * HD,        // v-slice only
                     att_wout, HD * HD,
                     out_w, HD * HD,
                     fin_w, 4 * HD,
                     sink);

  hipLaunchKernelGGL(head_kernel, dim3(16), dim3(256), 0, stream,
                     x, stats, ln0_g, ln0_b,
                     rb1_ln_g, rb1_ln_b, rb1_w1, rb1_b1, rb1_w2, rb1_b2, rb1_wp, rb1_bp,
                     rb2_ln_g, rb2_ln_b, rb2_w1, rb2_b1, rb2_w2, rb2_b2,
                     att_ln_g, att_ln_b, att_win, att_bin, att_wout, att_bout,
                     out_w, out_b, fin_w, fin_b, c_ws);

  hipLaunchKernelGGL(adj_tile_kernel, dim3(NT * (NT + 1) / 2, 16), dim3(256), 0, stream,
                     u, c_ws, out);
}

// Round 5
// 236.429 us; speedup vs baseline: 1.0659x; 1.0491x over previous
//
#include <hip/hip_runtime.h>
#include <math.h>

// ============================================================================
// Mathematical collapse of the reference:
//   h = broadcast(z) over N_NODES  =>  all nodes identical within a batch.
//   Every layer is per-node => h stays rank-1 (one vector per batch).
//   Attention: all scores equal => softmax uniform => o = mean_k(v) = v.
//   Edge logits la[b]+lb[b]+fin_b are ONE 2-vector c[b] for ALL pairs.
//   Straight-through gumbel: y = y_hard exactly (y_soft - y_soft == 0 bitwise).
//   tau = |temp| > 0 is argmax-invariant; argmax tie -> index 0 -> use >=.
//   => e[b,p] = (c0 + g0(u0) >= c1 + g1(u1)),  g(u) = -log(-log(u+1e-10)+1e-10)
//   => adj[b,i,j] = e at (min,max) pair, 0 on diagonal, symmetric.
//
// R4 lessons (rocprof):
//   - prefetch kernel: FETCH_SIZE of head unchanged (6.9MB), timed total
//     unchanged => weights are already L3-hot from the harness's input
//     restore; L3->L2 prefetch is worthless. DROPPED.
//   - head is load-QUEUE-limited: ~16k cy per matvec stage with only 256
//     lanes issuing. Fix: 1024 threads, 4-thread quads per output row
//     (4x outstanding loads), quad-combine via __shfl_xor(1|2).
// ============================================================================

#define NN    1024
#define HD    256
#define DIN0  71
#define NPAIR 523776   // 1024*1023/2
#define TILE  64
#define NT    16       // NN / TILE
#define HT    1024     // head threads (16 waves)

// ---------------------------------------------------------------------------
// head kernel helpers (f64, one 1024-thread block per batch)
// ---------------------------------------------------------------------------
__device__ __forceinline__ double blk_reduce(double v, double* red) {
  // intra-wave butterfly (64 lanes), then cross-wave via LDS (16 waves)
  #pragma unroll
  for (int m = 32; m > 0; m >>= 1) v += __shfl_xor(v, m, 64);
  const int wid = threadIdx.x >> 6;
  __syncthreads();                 // red[] free from any previous use
  if ((threadIdx.x & 63) == 0) red[wid] = v;
  __syncthreads();
  double s = 0.0;
  #pragma unroll
  for (int w = 0; w < HT / 64; ++w) s += red[w];  // fixed order on all threads
  return s;
}

// LayerNorm src -> dst over D elements (D <= 256). Safe for src == dst.
__device__ __forceinline__ void ln_to(const double* src, double* dst, int D,
                                      const float* __restrict__ gam,
                                      const float* __restrict__ bet,
                                      double* red) {
  const int tid = threadIdx.x;
  double v = (tid < D) ? src[tid] : 0.0;
  double m = blk_reduce(v, red) / (double)D;
  double d = (tid < D) ? (src[tid] - m) : 0.0;
  double var = blk_reduce(d * d, red) / (double)D;
  double inv = 1.0 / sqrt(var + (double)1e-5f);  // f32-rounded EPS, like jnp
  if (tid < D) dst[tid] = d * inv * (double)gam[tid] + (double)bet[tid];
  __syncthreads();
}

// Quarter-dot (part p of 4) of src[0..256) with W[row,:], f64 accumulate.
// float4 f = p+4k: for a fixed k, a wave's 64 lanes (16 rows x 4 parts)
// cover 16 complete 64B lines -> coalesced; 16 loads in flight per lane.
__device__ __forceinline__ double dot4_256(const double* src,
                                           const float* __restrict__ W,
                                           int row, int p) {
  const float4* w4 = reinterpret_cast<const float4*>(W + (size_t)row * 256);
  double a0 = 0.0, a1 = 0.0, a2 = 0.0, a3 = 0.0;
  #pragma unroll
  for (int k = 0; k < 16; ++k) {
    const int f = p + 4 * k;
    float4 w = w4[f];
    const double* s = src + 4 * f;
    a0 += s[0] * (double)w.x;
    a1 += s[1] * (double)w.y;
    a2 += s[2] * (double)w.z;
    a3 += s[3] * (double)w.w;
  }
  return (a0 + a1) + (a2 + a3);
}

// Quarter-dot over Din=71 (stride-4 scalar).
__device__ __forceinline__ double dot4_71(const double* src,
                                          const float* __restrict__ W,
                                          int row, int p) {
  const float* wr = W + (size_t)row * DIN0;
  double a = 0.0;
  #pragma unroll
  for (int i = p; i < DIN0; i += 4) a += src[i] * (double)wr[i];
  return a;
}

// Sum across the aligned 4-lane quad (lanes 4r..4r+3).
__device__ __forceinline__ double quad_sum(double v) {
  v += __shfl_xor(v, 1, 64);
  v += __shfl_xor(v, 2, 64);
  return v;
}

__device__ __forceinline__ double gelu_exact(double x) {
  return 0.5 * x * (1.0 + erf(x * 0.70710678118654752440));
}

__global__ __launch_bounds__(HT)
void head_kernel(const float* __restrict__ x, const float* __restrict__ stats,
                 const float* __restrict__ ln0_g, const float* __restrict__ ln0_b,
                 const float* __restrict__ rb1_ln_g, const float* __restrict__ rb1_ln_b,
                 const float* __restrict__ rb1_w1, const float* __restrict__ rb1_b1,
                 const float* __restrict__ rb1_w2, const float* __restrict__ rb1_b2,
                 const float* __restrict__ rb1_wp, const float* __restrict__ rb1_bp,
                 const float* __restrict__ rb2_ln_g, const float* __restrict__ rb2_ln_b,
                 const float* __restrict__ rb2_w1, const float* __restrict__ rb2_b1,
                 const float* __restrict__ rb2_w2, const float* __restrict__ rb2_b2,
                 const float* __restrict__ att_ln_g, const float* __restrict__ att_ln_b,
                 const float* __restrict__ att_win, const float* __restrict__ att_bin,
                 const float* __restrict__ att_wout, const float* __restrict__ att_bout,
                 const float* __restrict__ out_w, const float* __restrict__ out_b,
                 const float* __restrict__ fin_w, const float* __restrict__ fin_b,
                 double* __restrict__ c_out) {
  __shared__ double h[HD], t[HD], g[HD], red[HT / 64];
  const int tid = threadIdx.x;
  const int b = blockIdx.x;
  const int r = tid >> 2;        // output row 0..255
  const int p = tid & 3;         // quarter index

  // z = concat(x[b], stats[b])
  if (tid < DIN0)
    h[tid] = (tid < 64) ? (double)x[b * 64 + tid] : (double)stats[b * 7 + tid - 64];
  __syncthreads();

  // ln0 (in place)
  ln_to(h, h, DIN0, ln0_g, ln0_b, red);

  // ---- residual block 1 (D0 -> H, with projection) ----
  ln_to(h, t, DIN0, rb1_ln_g, rb1_ln_b, red);
  {
    double d = quad_sum(dot4_71(t, rb1_w1, r, p));
    if (p == 0) g[r] = gelu_exact(d + (double)rb1_b1[r]);
  }
  __syncthreads();
  {
    double d2 = quad_sum(dot4_256(g, rb1_w2, r, p));
    double dp = quad_sum(dot4_71(h, rb1_wp, r, p));
    __syncthreads();          // everyone done reading h[0..70]
    if (p == 0) h[r] = (d2 + (double)rb1_b2[r]) + (dp + (double)rb1_bp[r]);
  }
  __syncthreads();

  // ---- residual block 2 (H -> H) ----
  ln_to(h, t, HD, rb2_ln_g, rb2_ln_b, red);
  {
    double d = quad_sum(dot4_256(t, rb2_w1, r, p));
    if (p == 0) g[r] = gelu_exact(d + (double)rb2_b1[r]);
  }
  __syncthreads();
  {
    double d = quad_sum(dot4_256(g, rb2_w2, r, p));
    if (p == 0) h[r] = h[r] + (d + (double)rb2_b2[r]);  // own index; no hazard
  }
  __syncthreads();

  // ---- attention (collapses to o = v) ----
  ln_to(h, t, HD, att_ln_g, att_ln_b, red);
  {
    double d = quad_sum(dot4_256(t, att_win + 2 * HD * HD, r, p));  // v slice
    if (p == 0) g[r] = d + (double)att_bin[2 * HD + r];
  }
  __syncthreads();
  {
    double d = quad_sum(dot4_256(g, att_wout, r, p));
    if (p == 0) t[r] = d + (double)att_bout[r];
  }
  __syncthreads();
  {
    double d = quad_sum(dot4_256(t, out_w, r, p));
    if (p == 0) g[r] = d + (double)out_b[r];            // h_final in g
  }
  __syncthreads();

  // ---- edge logits: c[k] = sum_i h_i*(fin_w[k,i] + fin_w[k,H+i]) + fin_b[k] ----
  double v0 = 0.0, v1 = 0.0;
  if (tid < HD) {
    const double hj = g[tid];
    v0 = hj * (double)fin_w[tid]          + hj * (double)fin_w[HD + tid];
    v1 = hj * (double)fin_w[2 * HD + tid] + hj * (double)fin_w[3 * HD + tid];
  }
  double c0 = blk_reduce(v0, red) + (double)fin_b[0];
  double c1 = blk_reduce(v1, red) + (double)fin_b[1];
  if (tid == 0) {
    c_out[2 * b + 0] = c0;
    c_out[2 * b + 1] = c1;
  }
}

// ---------------------------------------------------------------------------
// adj tile-pair kernel
// grid = (136 tile-pairs, 16 batches), 256 threads.
// ---------------------------------------------------------------------------
__global__ __launch_bounds__(256)
void adj_tile_kernel(const float* __restrict__ u, const double* __restrict__ c,
                     float* __restrict__ out) {
  __shared__ float tile[TILE][TILE + 1];   // pad 65 -> <=2-way conflicts (free)
  const int b = blockIdx.y;
  int k = blockIdx.x;                       // 0..135 -> (ti, tj), ti <= tj
  int ti = 0;
  while (k >= NT - ti) { k -= NT - ti; ++ti; }
  const int tj = ti + k;
  const bool diag = (ti == tj);

  const int t        = threadIdx.x;
  const int lane_col = (t & 15) << 2;       // 0..60 step 4
  const int row_base = t >> 4;              // 0..15
  const double c0 = c[2 * b + 0];
  const double c1 = c[2 * b + 1];
  const float* ub = u + (size_t)b * (2u * NPAIR);
  float* ob = out + ((size_t)b << 20);

  // ---- stage 1: compute e, fill LDS; direct upper write for off-diag ----
  #pragma unroll
  for (int s = 0; s < 4; ++s) {
    const int il = s * 16 + row_base;
    const int i  = ti * TILE + il;
    const int rb = i * (2 * NN - 1 - i) / 2 - i - 1;   // p = rb + j  (for j>i)
    float4 ev4;
    float* ev = &ev4.x;
    #pragma unroll
    for (int q = 0; q < 4; ++q) {
      const int jl = lane_col + q;
      const int j  = tj * TILE + jl;
      float e = 0.0f;
      if (j > i) {
        const int p2 = rb + j;
        const float2 uu = *reinterpret_cast<const float2*>(ub + 2 * p2);
        // f32 hardware logs, mirroring the reference's own f32 ops.
        const float g0 = -logf(-logf(uu.x + 1e-10f) + 1e-10f);
        const float g1 = -logf(-logf(uu.y + 1e-10f) + 1e-10f);
        // Decision compare in f64 against the f64-accurate c.
        e = ((c0 + (double)g0) >= (c1 + (double)g1)) ? 1.0f : 0.0f;
      }
      ev[q] = e;
      tile[il][jl] = e;
    }
    if (!diag) {
      // coalesced float4 upper-tile write straight from registers
      *reinterpret_cast<float4*>(ob + (size_t)i * NN + tj * TILE + lane_col) = ev4;
    }
  }
  __syncthreads();

  // ---- stage 2: mirrored lower tile (off-diag) or full select (diag) ----
  #pragma unroll
  for (int s = 0; s < 4; ++s) {
    const int rl = s * 16 + row_base;
    if (!diag) {
      // lower tile row j = tj*64+rl, cols i = ti*64 + lane_col+q:
      // value = e(i, j) = tile[lane_col+q][rl]  (LDS transpose read, 2-way)
      float4 v = make_float4(tile[lane_col + 0][rl], tile[lane_col + 1][rl],
                             tile[lane_col + 2][rl], tile[lane_col + 3][rl]);
      *reinterpret_cast<float4*>(ob + (size_t)(tj * TILE + rl) * NN
                                    + ti * TILE + lane_col) = v;
    } else {
      float v[4];
      #pragma unroll
      for (int q = 0; q < 4; ++q) {
        const int jl = lane_col + q;
        v[q] = (jl > rl) ? tile[rl][jl] : ((jl < rl) ? tile[jl][rl] : 0.0f);
      }
      *reinterpret_cast<float4*>(ob + (size_t)(ti * TILE + rl) * NN
                                    + ti * TILE + lane_col)
          = make_float4(v[0], v[1], v[2], v[3]);
    }
  }
}

extern "C" void kernel_launch(void* const* d_in, const int* in_sizes, int n_in,
                              void* d_out, int out_size, void* d_ws, size_t ws_size,
                              hipStream_t stream) {
  const float* x        = (const float*)d_in[0];
  const float* stats    = (const float*)d_in[1];
  const float* u        = (const float*)d_in[2];
  const float* ln0_g    = (const float*)d_in[3];
  const float* ln0_b    = (const float*)d_in[4];
  const float* rb1_ln_g = (const float*)d_in[5];
  const float* rb1_ln_b = (const float*)d_in[6];
  const float* rb1_w1   = (const float*)d_in[7];
  const float* rb1_b1   = (const float*)d_in[8];
  const float* rb1_w2   = (const float*)d_in[9];
  const float* rb1_b2   = (const float*)d_in[10];
  const float* rb1_wp   = (const float*)d_in[11];
  const float* rb1_bp   = (const float*)d_in[12];
  const float* rb2_ln_g = (const float*)d_in[13];
  const float* rb2_ln_b = (const float*)d_in[14];
  const float* rb2_w1   = (const float*)d_in[15];
  const float* rb2_b1   = (const float*)d_in[16];
  const float* rb2_w2   = (const float*)d_in[17];
  const float* rb2_b2   = (const float*)d_in[18];
  const float* att_ln_g = (const float*)d_in[19];
  const float* att_ln_b = (const float*)d_in[20];
  const float* att_win  = (const float*)d_in[21];
  const float* att_bin  = (const float*)d_in[22];
  const float* att_wout = (const float*)d_in[23];
  const float* att_bout = (const float*)d_in[24];
  const float* out_w    = (const float*)d_in[25];
  const float* out_b    = (const float*)d_in[26];
  const float* fin_w    = (const float*)d_in[27];
  const float* fin_b    = (const float*)d_in[28];
  // d_in[29] = temp: tau = |temp| > 0 is argmax-invariant -> unused.

  double* c_ws = (double*)d_ws;          // 32 doubles
  float* out   = (float*)d_out;          // [16, 1024, 1024]

  hipLaunchKernelGGL(head_kernel, dim3(16), dim3(HT), 0, stream,
                     x, stats, ln0_g, ln0_b,
                     rb1_ln_g, rb1_ln_b, rb1_w1, rb1_b1, rb1_w2, rb1_b2, rb1_wp, rb1_bp,
                     rb2_ln_g, rb2_ln_b, rb2_w1, rb2_b1, rb2_w2, rb2_b2,
                     att_ln_g, att_ln_b, att_win, att_bin, att_wout, att_bout,
                     out_w, out_b, fin_w, fin_b, c_ws);

  hipLaunchKernelGGL(adj_tile_kernel, dim3(NT * (NT + 1) / 2, 16), dim3(256), 0, stream,
                     u, c_ws, out);
}

// Round 7
// 223.594 us; speedup vs baseline: 1.1271x; 1.0574x over previous
//
#include <hip/hip_runtime.h>
#include <math.h>

// ============================================================================
// Mathematical collapse of the reference:
//   h = broadcast(z) over N_NODES  =>  all nodes identical within a batch.
//   Attention: all scores equal => softmax uniform => o = mean_k(v) = v.
//   Edge logits are ONE 2-vector c[b] per batch; straight-through gumbel
//   forward-evals to y_hard; tau>0 argmax-invariant.
//   => e[b,p] = (c0 + g0(u0) >= c1 + g1(u1)),  g(u)=-log(-log(u+1e-10)+1e-10)
//   => adj[b,i,j] symmetric, 0 diagonal.
//
// R6 lesson: first call passed, post-timing diverged persistently (fresh
//   launches matched the WRONG output) => durable corruption. Cause: G/H/T
//   scratch grew d_ws usage to ~99KB, likely exceeding ws_size -> OOB writes
//   corrupted an adjacent durable buffer (e.g. pristine input copy).
// Fix: G/H/T scratch now lives in the TAIL OF d_out (64MB, guaranteed).
//   Head stages produce/consume it strictly BEFORE adj_tile_kernel, which
//   then overwrites all of d_out (stream order serializes). c stays in
//   d_ws[0..32) doubles (256B — proven safe in R3-R5).
//
// R5 lesson (rocprof): monolithic head latency-bound => 8 stage kernels,
//   64 blocks each (16 batches x 4 rowgroups), LN folded into consumers.
// ============================================================================

#define NN    1024
#define HD    256
#define DIN0  71
#define NPAIR 523776   // 1024*1023/2
#define TILE  64
#define NT    16       // NN / TILE

// ---------------------------------------------------------------------------
// shared helpers (256-thread blocks = 4 waves)
// ---------------------------------------------------------------------------
__device__ __forceinline__ double bred(double v, double* red4) {
  #pragma unroll
  for (int m = 32; m > 0; m >>= 1) v += __shfl_xor(v, m, 64);
  const int wid = threadIdx.x >> 6;
  __syncthreads();
  if ((threadIdx.x & 63) == 0) red4[wid] = v;
  __syncthreads();
  return (red4[0] + red4[1]) + (red4[2] + red4[3]);
}

__device__ __forceinline__ double quad_sum(double v) {
  v += __shfl_xor(v, 1, 64);
  v += __shfl_xor(v, 2, 64);
  return v;
}

// quarter-dot over 256 LDS doubles with f32 weight row (float4 loads)
__device__ __forceinline__ double dotq256(const double* s,
                                          const float* __restrict__ W,
                                          int row, int p) {
  const float4* w4 = reinterpret_cast<const float4*>(W + (size_t)row * 256);
  double a0 = 0.0, a1 = 0.0, a2 = 0.0, a3 = 0.0;
  #pragma unroll
  for (int k = 0; k < 16; ++k) {
    const int f = p + 4 * k;
    float4 w = w4[f];
    const double* sp = s + 4 * f;
    a0 += sp[0] * (double)w.x;
    a1 += sp[1] * (double)w.y;
    a2 += sp[2] * (double)w.z;
    a3 += sp[3] * (double)w.w;
  }
  return (a0 + a1) + (a2 + a3);
}

// quarter-dot over DIN0=71 LDS doubles (scalar, stride 4)
__device__ __forceinline__ double dotq71(const double* s,
                                         const float* __restrict__ W,
                                         int row, int p) {
  const float* wr = W + (size_t)row * DIN0;
  double a = 0.0;
  #pragma unroll
  for (int i = p; i < DIN0; i += 4) a += s[i] * (double)wr[i];
  return a;
}

__device__ __forceinline__ double gelu_exact(double x) {
  return 0.5 * x * (1.0 + erf(x * 0.70710678118654752440));
}

// compute ln0(z) for batch b into LDS h0[71] (threads 0..70 write)
__device__ __forceinline__ void ln0_into(const float* __restrict__ x,
                                         const float* __restrict__ stats,
                                         const float* __restrict__ g,
                                         const float* __restrict__ bb,
                                         int b, double* h0, double* red4) {
  const int tid = threadIdx.x;
  double z = 0.0;
  if (tid < DIN0)
    z = (tid < 64) ? (double)x[b * 64 + tid] : (double)stats[b * 7 + tid - 64];
  const double m = bred((tid < DIN0) ? z : 0.0, red4) / (double)DIN0;
  const double d = (tid < DIN0) ? (z - m) : 0.0;
  const double var = bred(d * d, red4) / (double)DIN0;
  const double inv = 1.0 / sqrt(var + (double)1e-5f);
  if (tid < DIN0) h0[tid] = d * inv * (double)g[tid] + (double)bb[tid];
  __syncthreads();
}

// ---------------------------------------------------------------------------
// K1: G = gelu(W1 @ rb1_ln(ln0(z)) + b1)        [64 blocks: b*4+rg]
// ---------------------------------------------------------------------------
__global__ __launch_bounds__(256)
void k1_ln_w1(const float* __restrict__ x, const float* __restrict__ stats,
              const float* __restrict__ ln0_g, const float* __restrict__ ln0_b,
              const float* __restrict__ l1g, const float* __restrict__ l1b,
              const float* __restrict__ W1, const float* __restrict__ b1,
              double* __restrict__ G) {
  __shared__ double t[DIN0], red[4];
  const int b = blockIdx.x >> 2, rg = blockIdx.x & 3;
  const int tid = threadIdx.x;
  ln0_into(x, stats, ln0_g, ln0_b, b, t, red);          // t = ln0(z)
  // second LN (rb1_ln) over t
  {
    double v = (tid < DIN0) ? t[tid] : 0.0;
    const double m = bred(v, red) / (double)DIN0;
    const double d = (tid < DIN0) ? (t[tid] - m) : 0.0;
    const double var = bred(d * d, red) / (double)DIN0;
    const double inv = 1.0 / sqrt(var + (double)1e-5f);
    __syncthreads();                                    // all reads of t done
    if (tid < DIN0) t[tid] = d * inv * (double)l1g[tid] + (double)l1b[tid];
    __syncthreads();
  }
  const int row = rg * 64 + (tid >> 2), p = tid & 3;
  const double d = quad_sum(dotq71(t, W1, row, p));
  if (p == 0) G[b * HD + row] = gelu_exact(d + (double)b1[row]);
}

// ---------------------------------------------------------------------------
// K2: H = (W2 @ G + b2) + (Wp @ ln0(z) + bp)    [64 blocks]
// ---------------------------------------------------------------------------
__global__ __launch_bounds__(256)
void k2_w2_wp(const float* __restrict__ x, const float* __restrict__ stats,
              const float* __restrict__ ln0_g, const float* __restrict__ ln0_b,
              const float* __restrict__ W2, const float* __restrict__ b2,
              const float* __restrict__ Wp, const float* __restrict__ bp,
              const double* __restrict__ G, double* __restrict__ H) {
  __shared__ double h0[DIN0], gs[HD], red[4];
  const int b = blockIdx.x >> 2, rg = blockIdx.x & 3;
  const int tid = threadIdx.x;
  gs[tid] = G[b * HD + tid];
  ln0_into(x, stats, ln0_g, ln0_b, b, h0, red);         // includes syncthreads
  const int row = rg * 64 + (tid >> 2), p = tid & 3;
  const double d2 = quad_sum(dotq256(gs, W2, row, p));
  const double dp = quad_sum(dotq71(h0, Wp, row, p));
  if (p == 0)
    H[b * HD + row] = (d2 + (double)b2[row]) + (dp + (double)bp[row]);
}

// ---------------------------------------------------------------------------
// K3: D = act(W @ LN(S) + bb)   (act = gelu if gelu_flag)   [64 blocks]
// ---------------------------------------------------------------------------
__global__ __launch_bounds__(256)
void k3_ln_mv(const double* __restrict__ S,
              const float* __restrict__ lg, const float* __restrict__ lb,
              const float* __restrict__ W, const float* __restrict__ bb,
              double* __restrict__ D, int gelu_flag) {
  __shared__ double t[HD], red[4];
  const int b = blockIdx.x >> 2, rg = blockIdx.x & 3;
  const int tid = threadIdx.x;
  const double s = S[b * HD + tid];
  const double m = bred(s, red) / (double)HD;
  const double d = s - m;
  const double var = bred(d * d, red) / (double)HD;
  const double inv = 1.0 / sqrt(var + (double)1e-5f);
  t[tid] = d * inv * (double)lg[tid] + (double)lb[tid];
  __syncthreads();
  const int row = rg * 64 + (tid >> 2), p = tid & 3;
  const double dd = quad_sum(dotq256(t, W, row, p));
  if (p == 0) {
    const double v = dd + (double)bb[row];
    D[b * HD + row] = gelu_flag ? gelu_exact(v) : v;
  }
}

// ---------------------------------------------------------------------------
// K4: H[row] += W @ G + bb   (residual add, own rows only)   [64 blocks]
// ---------------------------------------------------------------------------
__global__ __launch_bounds__(256)
void k4_mv_res(const double* __restrict__ G, const float* __restrict__ W,
               const float* __restrict__ bb, double* __restrict__ H) {
  __shared__ double gs[HD];
  const int b = blockIdx.x >> 2, rg = blockIdx.x & 3;
  const int tid = threadIdx.x;
  gs[tid] = G[b * HD + tid];
  __syncthreads();
  const int row = rg * 64 + (tid >> 2), p = tid & 3;
  const double d = quad_sum(dotq256(gs, W, row, p));
  if (p == 0) H[b * HD + row] += d + (double)bb[row];
}

// ---------------------------------------------------------------------------
// K5: D = W @ S + bb   (plain matvec)   [64 blocks]
// ---------------------------------------------------------------------------
__global__ __launch_bounds__(256)
void k5_mv(const double* __restrict__ S, const float* __restrict__ W,
           const float* __restrict__ bb, double* __restrict__ D) {
  __shared__ double ss[HD];
  const int b = blockIdx.x >> 2, rg = blockIdx.x & 3;
  const int tid = threadIdx.x;
  ss[tid] = S[b * HD + tid];
  __syncthreads();
  const int row = rg * 64 + (tid >> 2), p = tid & 3;
  const double d = quad_sum(dotq256(ss, W, row, p));
  if (p == 0) D[b * HD + row] = d + (double)bb[row];
}

// ---------------------------------------------------------------------------
// K6: c[b] from h_final                                  [16 blocks]
// ---------------------------------------------------------------------------
__global__ __launch_bounds__(256)
void k6_fin(const double* __restrict__ Hf, const float* __restrict__ fin_w,
            const float* __restrict__ fin_b, double* __restrict__ c_out) {
  __shared__ double red[4];
  const int b = blockIdx.x;
  const int tid = threadIdx.x;
  const double hj = Hf[b * HD + tid];
  const double v0 = hj * (double)fin_w[tid]          + hj * (double)fin_w[HD + tid];
  const double v1 = hj * (double)fin_w[2 * HD + tid] + hj * (double)fin_w[3 * HD + tid];
  const double c0 = bred(v0, red) + (double)fin_b[0];
  const double c1 = bred(v1, red) + (double)fin_b[1];
  if (tid == 0) {
    c_out[2 * b + 0] = c0;
    c_out[2 * b + 1] = c1;
  }
}

// ---------------------------------------------------------------------------
// adj tile-pair kernel (unchanged since R4 — absmax 0.0)
// grid = (136 tile-pairs, 16 batches), 256 threads.
// NOTE: overwrites ALL of d_out, including the scratch tail used by K1-K6
// (which is fully consumed by the time this kernel runs — same stream).
// ---------------------------------------------------------------------------
__global__ __launch_bounds__(256)
void adj_tile_kernel(const float* __restrict__ u, const double* __restrict__ c,
                     float* __restrict__ out) {
  __shared__ float tile[TILE][TILE + 1];   // pad 65 -> <=2-way conflicts (free)
  const int b = blockIdx.y;
  int k = blockIdx.x;                       // 0..135 -> (ti, tj), ti <= tj
  int ti = 0;
  while (k >= NT - ti) { k -= NT - ti; ++ti; }
  const int tj = ti + k;
  const bool diag = (ti == tj);

  const int t        = threadIdx.x;
  const int lane_col = (t & 15) << 2;       // 0..60 step 4
  const int row_base = t >> 4;              // 0..15
  const double c0 = c[2 * b + 0];
  const double c1 = c[2 * b + 1];
  const float* ub = u + (size_t)b * (2u * NPAIR);
  float* ob = out + ((size_t)b << 20);

  #pragma unroll
  for (int s = 0; s < 4; ++s) {
    const int il = s * 16 + row_base;
    const int i  = ti * TILE + il;
    const int rb = i * (2 * NN - 1 - i) / 2 - i - 1;   // p = rb + j  (for j>i)
    float4 ev4;
    float* ev = &ev4.x;
    #pragma unroll
    for (int q = 0; q < 4; ++q) {
      const int jl = lane_col + q;
      const int j  = tj * TILE + jl;
      float e = 0.0f;
      if (j > i) {
        const int p2 = rb + j;
        const float2 uu = *reinterpret_cast<const float2*>(ub + 2 * p2);
        const float g0 = -logf(-logf(uu.x + 1e-10f) + 1e-10f);
        const float g1 = -logf(-logf(uu.y + 1e-10f) + 1e-10f);
        e = ((c0 + (double)g0) >= (c1 + (double)g1)) ? 1.0f : 0.0f;
      }
      ev[q] = e;
      tile[il][jl] = e;
    }
    if (!diag) {
      *reinterpret_cast<float4*>(ob + (size_t)i * NN + tj * TILE + lane_col) = ev4;
    }
  }
  __syncthreads();

  #pragma unroll
  for (int s = 0; s < 4; ++s) {
    const int rl = s * 16 + row_base;
    if (!diag) {
      float4 v = make_float4(tile[lane_col + 0][rl], tile[lane_col + 1][rl],
                             tile[lane_col + 2][rl], tile[lane_col + 3][rl]);
      *reinterpret_cast<float4*>(ob + (size_t)(tj * TILE + rl) * NN
                                    + ti * TILE + lane_col) = v;
    } else {
      float v[4];
      #pragma unroll
      for (int q = 0; q < 4; ++q) {
        const int jl = lane_col + q;
        v[q] = (jl > rl) ? tile[rl][jl] : ((jl < rl) ? tile[jl][rl] : 0.0f);
      }
      *reinterpret_cast<float4*>(ob + (size_t)(ti * TILE + rl) * NN
                                    + ti * TILE + lane_col)
          = make_float4(v[0], v[1], v[2], v[3]);
    }
  }
}

extern "C" void kernel_launch(void* const* d_in, const int* in_sizes, int n_in,
                              void* d_out, int out_size, void* d_ws, size_t ws_size,
                              hipStream_t stream) {
  const float* x        = (const float*)d_in[0];
  const float* stats    = (const float*)d_in[1];
  const float* u        = (const float*)d_in[2];
  const float* ln0_g    = (const float*)d_in[3];
  const float* ln0_b    = (const float*)d_in[4];
  const float* rb1_ln_g = (const float*)d_in[5];
  const float* rb1_ln_b = (const float*)d_in[6];
  const float* rb1_w1   = (const float*)d_in[7];
  const float* rb1_b1   = (const float*)d_in[8];
  const float* rb1_w2   = (const float*)d_in[9];
  const float* rb1_b2   = (const float*)d_in[10];
  const float* rb1_wp   = (const float*)d_in[11];
  const float* rb1_bp   = (const float*)d_in[12];
  const float* rb2_ln_g = (const float*)d_in[13];
  const float* rb2_ln_b = (const float*)d_in[14];
  const float* rb2_w1   = (const float*)d_in[15];
  const float* rb2_b1   = (const float*)d_in[16];
  const float* rb2_w2   = (const float*)d_in[17];
  const float* rb2_b2   = (const float*)d_in[18];
  const float* att_ln_g = (const float*)d_in[19];
  const float* att_ln_b = (const float*)d_in[20];
  const float* att_win  = (const float*)d_in[21];
  const float* att_bin  = (const float*)d_in[22];
  const float* att_wout = (const float*)d_in[23];
  const float* att_bout = (const float*)d_in[24];
  const float* out_w    = (const float*)d_in[25];
  const float* out_b    = (const float*)d_in[26];
  const float* fin_w    = (const float*)d_in[27];
  const float* fin_b    = (const float*)d_in[28];
  // d_in[29] = temp: tau = |temp| > 0 is argmax-invariant -> unused.

  float* out   = (float*)d_out;            // [16, 1024, 1024] = 64MB
  double* c_ws = (double*)d_ws;            // 32 doubles (256B — safe)

  // G/H/T scratch in the TAIL of d_out (3 x 16 x 256 doubles = 96KB).
  // Consumed entirely before adj_tile_kernel overwrites all of d_out.
  double* G = (double*)(out + ((size_t)16 * NN * NN - 3 * 16 * HD * 2));
  double* H = G + 16 * HD;
  double* T = H + 16 * HD;

  const dim3 g64(64), t256(256);
  hipLaunchKernelGGL(k1_ln_w1, g64, t256, 0, stream,
                     x, stats, ln0_g, ln0_b, rb1_ln_g, rb1_ln_b,
                     rb1_w1, rb1_b1, G);
  hipLaunchKernelGGL(k2_w2_wp, g64, t256, 0, stream,
                     x, stats, ln0_g, ln0_b, rb1_w2, rb1_b2, rb1_wp, rb1_bp,
                     G, H);
  hipLaunchKernelGGL(k3_ln_mv, g64, t256, 0, stream,
                     H, rb2_ln_g, rb2_ln_b, rb2_w1, rb2_b1, G, 1);
  hipLaunchKernelGGL(k4_mv_res, g64, t256, 0, stream,
                     G, rb2_w2, rb2_b2, H);
  hipLaunchKernelGGL(k3_ln_mv, g64, t256, 0, stream,
                     H, att_ln_g, att_ln_b, att_win + 2 * HD * HD,
                     att_bin + 2 * HD, G, 0);
  hipLaunchKernelGGL(k5_mv, g64, t256, 0, stream, G, att_wout, att_bout, T);
  hipLaunchKernelGGL(k5_mv, g64, t256, 0, stream, T, out_w, out_b, G);
  hipLaunchKernelGGL(k6_fin, dim3(16), t256, 0, stream, G, fin_w, fin_b, c_ws);

  hipLaunchKernelGGL(adj_tile_kernel, dim3(NT * (NT + 1) / 2, 16), t256, 0, stream,
                     u, c_ws, out);
}